// Round 8
// baseline (91.487 us; speedup 1.0000x reference)
//
#include <hip/hip_runtime.h>

#define H_ 128
#define W_ 128
#define HW 16384
#define C_ 64
#define O_ 64
#define N_ 8

typedef __attribute__((ext_vector_type(4))) float f32x4;
typedef __attribute__((ext_vector_type(2))) _Float16 f16x2;
typedef __attribute__((ext_vector_type(8))) _Float16 f16x8;

__device__ __forceinline__ unsigned short f2h(float f) {
    union { _Float16 h; unsigned short u; } c;
    c.h = (_Float16)f;
    return c.u;
}

// ---- prep 1: x NCHW fp32 -> xt NHWC f16, XCD-aligned (n = bid&7) ----
__global__ __launch_bounds__(256) void nchw2nhwc(const float* __restrict__ x,
                                                 unsigned short* __restrict__ xt) {
    const int bid = blockIdx.x;
    const int n = bid & 7;
    const int rest = bid >> 3;
    const int wt = rest & 3, h = rest >> 2;
    const int w0 = wt * 32;
    __shared__ unsigned short tile[32][65];
    const int tid = threadIdx.x;
    const int wl = tid & 31, cg = tid >> 5;
#pragma unroll
    for (int r = 0; r < 8; ++r) {
        const int c = cg * 8 + r;
        const float v = x[(((size_t)(n * 64 + c) * 128 + h) * 128) + w0 + wl];
        tile[wl][c] = f2h(v);
    }
    __syncthreads();
    const int c2 = tid & 63, wg = tid >> 6;
#pragma unroll
    for (int r = 0; r < 8; ++r) {
        const int w = wg * 8 + r;
        xt[(((size_t)(n * 128 + h) * 128 + w0 + w) << 6) + c2] = tile[w][c2];
    }
}

// ---- prep 2: weight [O][C][3][3] fp32 -> B-fragment-packed f16 ----
// ushort idx = q*512 + lane*8 + i ; q = (j*2+h)*4 + ot
// o = ot*16 + (lane&15) ; c = h*32 + (lane>>4)*8 + i
__global__ void bpack_kernel(const float* __restrict__ w, unsigned short* __restrict__ bp) {
    const int idx = blockIdx.x * 256 + threadIdx.x;
    if (idx >= 36864) return;
    const int i = idx & 7;
    const int lane = (idx >> 3) & 63;
    const int ot = (idx >> 9) & 3;
    const int h = (idx >> 11) & 1;
    const int j = idx >> 12;
    const int o = ot * 16 + (lane & 15);
    const int c = h * 32 + (lane >> 4) * 8 + i;
    bp[idx] = f2h(w[(o * 64 + c) * 9 + j]);
}

// ---- main: 16x32 output tile / 512-thread block; FULL 64-ch halo staged once ----
// Halo 28x44 positions x 128B = 157,696 B LDS.
// Position p=(ry,rx): 8 x 16B chunks stored at  p*8 + (chunk ^ (rx&7)).
// bank(byte) = byte/4 %32; position stride 128B == 0 mod banks, so bank is a
// function of the stored chunk slot only; the 3-bit XOR by local x makes each
// wave's 64-lane b128 read hit each 16B slot exactly 8x (uniform) -> minimal
// 8-cycle schedule, no conflicts. Read for K-half h: idx_h = idx_h0 ^ (h*4).
__global__ __launch_bounds__(512, 1) void dcn_mfma(const unsigned short* __restrict__ xt,
                                                   const float* __restrict__ off,
                                                   const unsigned short* __restrict__ bp,
                                                   float* __restrict__ out) {
    __shared__ uint4 lds4[9856];   // 28*44*8 chunks = 157,696 B

    const int tid = threadIdx.x;
    const int lane = tid & 63;
    const int wid = tid >> 6;          // 8 waves
    const int lrow = lane & 15;        // pixel within strip; o in epilogue
    const int lgrp = lane >> 4;        // k-group

    const int bid = blockIdx.x;
    const int n = bid & 7;             // XCD-pinned image
    const int tile = bid >> 3;         // 0..31
    const int t   = (tile >> 2) << 4;  // tile row origin (8 rows of tiles)
    const int tx0 = (tile & 3) << 5;   // tile col origin (4 cols of tiles)

    const unsigned short* xn = xt + (size_t)n * (HW * 64);
    const unsigned char* xb = (const unsigned char*)xn;
    const f16x8* bg = (const f16x8*)bp;
    const float* offn = off + (size_t)n * 18 * HW;

    // ---- stage full halo (64 ch), coalesced, swizzled ----
    for (int i = tid; i < 9856; i += 512) {
        const int pos = i >> 3, sub = i & 7;
        const int ry = pos / 44, rx = pos - ry * 44;
        const int gy = min(max(t - 6 + ry, 0), 127);
        const int gx = min(max(tx0 - 6 + rx, 0), 127);
        const uint4* src = (const uint4*)(xn + (((gy << 7) + gx) << 6));
        lds4[(pos << 3) + (sub ^ (rx & 7))] = src[sub];
    }
    __syncthreads();

    // ---- compute: 4 strips per wave (strip = 16 px along w), 9 taps, 2 K-halves ----
#pragma unroll 1
    for (int q = 0; q < 4; ++q) {
        const int strip = (wid << 2) + q;      // 0..31
        const int srow = strip >> 1, shalf = strip & 1;
        const int ho = t + srow;
        const int wo = tx0 + (shalf << 4) + lrow;
        const int pix = (ho << 7) + wo;
        const float fho = (float)(ho - 1);
        const float fwo = (float)(wo - 1);

        float offs[18];
#pragma unroll
        for (int ch = 0; ch < 18; ++ch) offs[ch] = offn[(size_t)ch * HW + pix];

        f32x4 acc0 = {0.f,0.f,0.f,0.f}, acc1 = {0.f,0.f,0.f,0.f};
        f32x4 acc2 = {0.f,0.f,0.f,0.f}, acc3 = {0.f,0.f,0.f,0.f};

#pragma unroll
        for (int j = 0; j < 9; ++j) {
            const int kh = j / 3, kw = j % 3;
            const float oy = offs[2 * j];
            const float ox = offs[2 * j + 1];
            const float py = fho + (float)kh + oy;
            const float px = fwo + (float)kw + ox;
            const float y0f = floorf(py), x0f = floorf(px);
            const float wy = py - y0f, wx = px - x0f;
            const int y0 = (int)y0f, xx0 = (int)x0f;
            const bool vy0 = (unsigned)y0 < 128u;
            const bool vy1 = (unsigned)(y0 + 1) < 128u;
            const bool vx0 = (unsigned)xx0 < 128u;
            const bool vx1 = (unsigned)(xx0 + 1) < 128u;
            const int y0c = min(max(y0, 0), 127), y1c = min(max(y0 + 1, 0), 127);
            const int x0c = min(max(xx0, 0), 127), x1c = min(max(xx0 + 1, 0), 127);
            const float s00 = (1.f - wy) * (1.f - wx) * ((vy0 & vx0) ? 1.f : 0.f);
            const float s01 = (1.f - wy) * wx * ((vy0 & vx1) ? 1.f : 0.f);
            const float s10 = wy * (1.f - wx) * ((vy1 & vx0) ? 1.f : 0.f);
            const float s11 = wy * wx * ((vy1 & vx1) ? 1.f : 0.f);
            const _Float16 h00 = (_Float16)s00, h01 = (_Float16)s01;
            const _Float16 h10 = (_Float16)s10, h11 = (_Float16)s11;
            const f16x2 W00 = {h00, h00}, W01 = {h01, h01};
            const f16x2 W10 = {h10, h10}, W11 = {h11, h11};

            // local halo coords
            const int sy0 = y0c - t + 6, sy1 = y1c - t + 6;
            const int sx0 = x0c - tx0 + 6, sx1 = x1c - tx0 + 6;
            const bool ok = ((unsigned)sy0 <= 27u) & ((unsigned)sy1 <= 27u) &
                            ((unsigned)sx0 <= 43u) & ((unsigned)sx1 <= 43u);
            const int cy0 = min(max(sy0, 0), 27), cy1 = min(max(sy1, 0), 27);
            const int cx0 = min(max(sx0, 0), 43), cx1 = min(max(sx1, 0), 43);
            const int g0 = lgrp ^ (cx0 & 7), g1 = lgrp ^ (cx1 & 7);
            const int i00 = ((cy0 * 44 + cx0) << 3) + g0;
            const int i01 = ((cy0 * 44 + cx1) << 3) + g1;
            const int i10 = ((cy1 * 44 + cx0) << 3) + g0;
            const int i11 = ((cy1 * 44 + cx1) << 3) + g1;
            const bool allok = __all(ok);

#pragma unroll
            for (int h = 0; h < 2; ++h) {
                const int hx = h << 2;
                uint4 T00 = lds4[i00 ^ hx];
                uint4 T01 = lds4[i01 ^ hx];
                uint4 T10 = lds4[i10 ^ hx];
                uint4 T11 = lds4[i11 ^ hx];
                if (!allok) {   // rare: tap beyond halo -> exact global path (per lane)
                    if (!ok) {
                        const unsigned char* p = xb + ((((y0c << 7) + x0c) << 7) | (h << 6)) + (lgrp << 4);
                        const int dxo = (x1c - x0c) << 7;
                        const int dyo = (y1c - y0c) << 14;
                        T00 = *(const uint4*)p;
                        T01 = *(const uint4*)(p + dxo);
                        T10 = *(const uint4*)(p + dyo);
                        T11 = *(const uint4*)(p + dyo + dxo);
                    }
                }
                union { uint4 u; f16x2 h2[4]; f16x8 v; } A, U00, U01, U10, U11;
                U00.u = T00; U01.u = T01; U10.u = T10; U11.u = T11;
#pragma unroll
                for (int k = 0; k < 4; ++k)
                    A.h2[k] = U00.h2[k] * W00 + U01.h2[k] * W01
                            + U10.h2[k] * W10 + U11.h2[k] * W11;
                const int fb = ((j * 2 + h) << 8) + lane;
                acc0 = __builtin_amdgcn_mfma_f32_16x16x32_f16(A.v, bg[fb],       acc0, 0, 0, 0);
                acc1 = __builtin_amdgcn_mfma_f32_16x16x32_f16(A.v, bg[fb + 64],  acc1, 0, 0, 0);
                acc2 = __builtin_amdgcn_mfma_f32_16x16x32_f16(A.v, bg[fb + 128], acc2, 0, 0, 0);
                acc3 = __builtin_amdgcn_mfma_f32_16x16x32_f16(A.v, bg[fb + 192], acc3, 0, 0, 0);
            }
        }

        // epilogue: o = qo*16 + lrow plane, pixel = strip_base + lgrp*4 + r
        float* opb = out + (size_t)n * (O_ * HW) + ((size_t)ho << 7) + tx0 + (shalf << 4) + lgrp * 4;
        *(f32x4*)(opb + (size_t)(0 * 16 + lrow) * HW) = acc0;
        *(f32x4*)(opb + (size_t)(1 * 16 + lrow) * HW) = acc1;
        *(f32x4*)(opb + (size_t)(2 * 16 + lrow) * HW) = acc2;
        *(f32x4*)(opb + (size_t)(3 * 16 + lrow) * HW) = acc3;
    }
}

extern "C" void kernel_launch(void* const* d_in, const int* in_sizes, int n_in,
                              void* d_out, int out_size, void* d_ws, size_t ws_size,
                              hipStream_t stream) {
    const float* x = (const float*)d_in[0];
    const float* off = (const float*)d_in[1];
    const float* w = (const float*)d_in[2];
    float* out = (float*)d_out;

    unsigned short* bp = (unsigned short*)d_ws;                  // 73728 B
    unsigned short* xt = (unsigned short*)((char*)d_ws + 73728); // 16.8 MB

    bpack_kernel<<<144, 256, 0, stream>>>(w, bp);
    nchw2nhwc<<<4096, 256, 0, stream>>>(x, xt);

    dcn_mfma<<<256, 512, 0, stream>>>(xt, off, bp, out);
}

// Round 9
// 70.612 us; speedup vs baseline: 1.2956x; 1.2956x over previous
//
#include <hip/hip_runtime.h>

#define H_ 128
#define W_ 128
#define HW 16384
#define C_ 64
#define O_ 64
#define N_ 8

typedef __attribute__((ext_vector_type(4))) float f32x4;
typedef __attribute__((ext_vector_type(2))) _Float16 f16x2;
typedef __attribute__((ext_vector_type(8))) _Float16 f16x8;

__device__ __forceinline__ unsigned short f2h(float f) {
    union { _Float16 h; unsigned short u; } c;
    c.h = (_Float16)f;
    return c.u;
}

// ---- prep 1: x NCHW fp32 -> xt NHWC f16, XCD-aligned (n = bid&7) ----
__global__ __launch_bounds__(256) void nchw2nhwc(const float* __restrict__ x,
                                                 unsigned short* __restrict__ xt) {
    const int bid = blockIdx.x;
    const int n = bid & 7;
    const int rest = bid >> 3;
    const int wt = rest & 3, h = rest >> 2;
    const int w0 = wt * 32;
    __shared__ unsigned short tile[32][65];
    const int tid = threadIdx.x;
    const int wl = tid & 31, cg = tid >> 5;
#pragma unroll
    for (int r = 0; r < 8; ++r) {
        const int c = cg * 8 + r;
        const float v = x[(((size_t)(n * 64 + c) * 128 + h) * 128) + w0 + wl];
        tile[wl][c] = f2h(v);
    }
    __syncthreads();
    const int c2 = tid & 63, wg = tid >> 6;
#pragma unroll
    for (int r = 0; r < 8; ++r) {
        const int w = wg * 8 + r;
        xt[(((size_t)(n * 128 + h) * 128 + w0 + w) << 6) + c2] = tile[w][c2];
    }
}

// ---- prep 2: weight [O][C][3][3] fp32 -> B-fragment-packed f16 ----
// ushort idx = q*512 + lane*8 + i ; q = (j*2+h)*4 + ot
// o = ot*16 + (lane&15) ; c = h*32 + (lane>>4)*8 + i
__global__ void bpack_kernel(const float* __restrict__ w, unsigned short* __restrict__ bp) {
    const int idx = blockIdx.x * 256 + threadIdx.x;
    if (idx >= 36864) return;
    const int i = idx & 7;
    const int lane = (idx >> 3) & 63;
    const int ot = (idx >> 9) & 3;
    const int h = (idx >> 11) & 1;
    const int j = idx >> 12;
    const int o = ot * 16 + (lane & 15);
    const int c = h * 32 + (lane >> 4) * 8 + i;
    bp[idx] = f2h(w[(o * 64 + c) * 9 + j]);
}

// ---- main: 16x16 output tile per block; halo staged in LDS (28x28, 32ch per pass) ----
// LDS layout (per h-half): position (ry,rx) -> 4 x 16B chunks at 16B-index
//   (ry*28+rx)*4 + (sub ^ (rx&3))
// Swizzle is by COLUMN (rx), not row: within a wave, the 16 lanes of a row-group
// read 16 consecutive x at the same tap row. Row-based swizzle gave them all the
// same chunk slot -> 2 distinct bank-quads per 16 lanes -> ~8-way conflicts
// (round 7: 5.28M conflict cycles). x-based swizzle cycles all 8 quads ->
// 2 lanes/quad = free b128 minimum.
__global__ __launch_bounds__(256, 3) void dcn_mfma(const unsigned short* __restrict__ xt,
                                                   const float* __restrict__ off,
                                                   const unsigned short* __restrict__ bp,
                                                   float* __restrict__ out) {
    __shared__ uint4 lds4[3136];   // 28*28*64B = 50176 B  (3 blocks/CU)

    const int tid = threadIdx.x;
    const int lane = tid & 63;
    const int wid = tid >> 6;
    const int lrow = lane & 15;   // pixel within strip (A-row); o in epilogue
    const int lgrp = lane >> 4;   // k-group

    const int bid = blockIdx.x;
    const int n = bid & 7;               // XCD-pinned image
    const int tile = bid >> 3;           // 0..63
    const int t   = (tile >> 3) << 4;    // tile row origin
    const int tx0 = (tile & 7) << 4;     // tile col origin

    const unsigned short* xn = xt + (size_t)n * (HW * 64);
    const unsigned char* xb = (const unsigned char*)xn;
    const f16x8* bg = (const f16x8*)bp;
    const float* offn = off + (size_t)n * 18 * HW;

    f32x4 acc[4][4];
#pragma unroll
    for (int q = 0; q < 4; ++q)
#pragma unroll
        for (int r = 0; r < 4; ++r) acc[q][r] = (f32x4){0.f, 0.f, 0.f, 0.f};

#pragma unroll 1
    for (int h = 0; h < 2; ++h) {
        if (h) __syncthreads();   // all reads of previous half done before overwrite
        // ---- stage halo half (32 channels) : coalesced global -> LDS ----
        for (int c = tid; c < 784; c += 256) {
            const int ry = c / 28, rx = c - ry * 28;
            const int gy = min(max(t - 6 + ry, 0), 127);
            const int gx = min(max(tx0 - 6 + rx, 0), 127);
            const uint4* src = (const uint4*)(xn + ((((gy << 7) + gx) << 6) | (h << 5)));
            const int d = c << 2, sw = rx & 3;
#pragma unroll
            for (int sub = 0; sub < 4; ++sub) lds4[d + (sub ^ sw)] = src[sub];
        }
        __syncthreads();

        // ---- compute: 4 strips per wave, 9 taps, K-half h ----
#pragma unroll
        for (int q = 0; q < 4; ++q) {
            const int ho = t + wid * 4 + q;
            const int wo = tx0 + lrow;
            const int pix = (ho << 7) + wo;
            const float fho = (float)(ho - 1);
            const float fwo = (float)(wo - 1);

#pragma unroll 1
            for (int jo = 0; jo < 3; ++jo) {   // kh = jo
                const float* ob = offn + (size_t)(6 * jo) * HW + pix;
                const float o0 = ob[0];
                const float o1 = ob[(size_t)1 * HW];
                const float o2 = ob[(size_t)2 * HW];
                const float o3 = ob[(size_t)3 * HW];
                const float o4 = ob[(size_t)4 * HW];
                const float o5 = ob[(size_t)5 * HW];
#pragma unroll
                for (int ji = 0; ji < 3; ++ji) {   // kw = ji
                    const float oy = (ji == 0) ? o0 : (ji == 1) ? o2 : o4;
                    const float ox = (ji == 0) ? o1 : (ji == 1) ? o3 : o5;
                    const float py = fho + (float)jo + oy;
                    const float px = fwo + (float)ji + ox;
                    const float y0f = floorf(py), x0f = floorf(px);
                    const float wy = py - y0f, wx = px - x0f;
                    const int y0 = (int)y0f, xx0 = (int)x0f;
                    const bool vy0 = (unsigned)y0 < 128u;
                    const bool vy1 = (unsigned)(y0 + 1) < 128u;
                    const bool vx0 = (unsigned)xx0 < 128u;
                    const bool vx1 = (unsigned)(xx0 + 1) < 128u;
                    const int y0c = min(max(y0, 0), 127), y1c = min(max(y0 + 1, 0), 127);
                    const int x0c = min(max(xx0, 0), 127), x1c = min(max(xx0 + 1, 0), 127);
                    const float s00 = (1.f - wy) * (1.f - wx) * ((vy0 & vx0) ? 1.f : 0.f);
                    const float s01 = (1.f - wy) * wx * ((vy0 & vx1) ? 1.f : 0.f);
                    const float s10 = wy * (1.f - wx) * ((vy1 & vx0) ? 1.f : 0.f);
                    const float s11 = wy * wx * ((vy1 & vx1) ? 1.f : 0.f);
                    const _Float16 h00 = (_Float16)s00, h01 = (_Float16)s01;
                    const _Float16 h10 = (_Float16)s10, h11 = (_Float16)s11;
                    const f16x2 W00 = {h00, h00}, W01 = {h01, h01};
                    const f16x2 W10 = {h10, h10}, W11 = {h11, h11};

                    // in-halo slots
                    const int sy0 = y0c - t + 6, sy1 = y1c - t + 6;
                    const int sx0 = x0c - tx0 + 6, sx1 = x1c - tx0 + 6;
                    const bool ok = ((unsigned)sy0 <= 27u) & ((unsigned)sy1 <= 27u) &
                                    ((unsigned)sx0 <= 27u) & ((unsigned)sx1 <= 27u);
                    const int cy0 = min(max(sy0, 0), 27), cy1 = min(max(sy1, 0), 27);
                    const int cx0 = min(max(sx0, 0), 27), cx1 = min(max(sx1, 0), 27);
                    const int r0 = cy0 * 28, r1 = cy1 * 28;
                    const int gx0 = lgrp ^ (cx0 & 3), gx1 = lgrp ^ (cx1 & 3);
                    uint4 T00 = lds4[((r0 + cx0) << 2) + gx0];
                    uint4 T01 = lds4[((r0 + cx1) << 2) + gx1];
                    uint4 T10 = lds4[((r1 + cx0) << 2) + gx0];
                    uint4 T11 = lds4[((r1 + cx1) << 2) + gx1];
                    if (!__all(ok)) {   // ~never taken: offset beyond halo -> exact global path
                        if (!ok) {
                            const unsigned char* p = xb + ((((y0c << 7) + x0c) << 7) | (h << 6)) + (lgrp << 4);
                            const int dxo = (x1c - x0c) << 7;
                            const int dyo = (y1c - y0c) << 14;
                            T00 = *(const uint4*)p;
                            T01 = *(const uint4*)(p + dxo);
                            T10 = *(const uint4*)(p + dyo);
                            T11 = *(const uint4*)(p + dyo + dxo);
                        }
                    }
                    union { uint4 u; f16x2 h2[4]; f16x8 v; } A, U00, U01, U10, U11;
                    U00.u = T00; U01.u = T01; U10.u = T10; U11.u = T11;
#pragma unroll
                    for (int k = 0; k < 4; ++k)
                        A.h2[k] = U00.h2[k] * W00 + U01.h2[k] * W01
                                + U10.h2[k] * W10 + U11.h2[k] * W11;
                    const int j = jo * 3 + ji;
                    const int fb = ((j * 2 + h) << 8) + lane;   // ((j*2+h)*4)*64 + lane
                    acc[q][0] = __builtin_amdgcn_mfma_f32_16x16x32_f16(A.v, bg[fb],       acc[q][0], 0, 0, 0);
                    acc[q][1] = __builtin_amdgcn_mfma_f32_16x16x32_f16(A.v, bg[fb + 64],  acc[q][1], 0, 0, 0);
                    acc[q][2] = __builtin_amdgcn_mfma_f32_16x16x32_f16(A.v, bg[fb + 128], acc[q][2], 0, 0, 0);
                    acc[q][3] = __builtin_amdgcn_mfma_f32_16x16x32_f16(A.v, bg[fb + 192], acc[q][3], 0, 0, 0);
                }
            }
        }
    }

    // epilogue: o = qq*16 + lrow plane, pixel = strip_base + lgrp*4 + r (validated r2-r7)
#pragma unroll
    for (int q = 0; q < 4; ++q) {
        float* opb = out + (size_t)n * (O_ * HW) + ((t + wid * 4 + q) << 7) + tx0 + lgrp * 4;
        *(f32x4*)(opb + (size_t)(0 * 16 + lrow) * HW) = acc[q][0];
        *(f32x4*)(opb + (size_t)(1 * 16 + lrow) * HW) = acc[q][1];
        *(f32x4*)(opb + (size_t)(2 * 16 + lrow) * HW) = acc[q][2];
        *(f32x4*)(opb + (size_t)(3 * 16 + lrow) * HW) = acc[q][3];
    }
}

extern "C" void kernel_launch(void* const* d_in, const int* in_sizes, int n_in,
                              void* d_out, int out_size, void* d_ws, size_t ws_size,
                              hipStream_t stream) {
    const float* x = (const float*)d_in[0];
    const float* off = (const float*)d_in[1];
    const float* w = (const float*)d_in[2];
    float* out = (float*)d_out;

    unsigned short* bp = (unsigned short*)d_ws;                  // 73728 B
    unsigned short* xt = (unsigned short*)((char*)d_ws + 73728); // 16.8 MB

    bpack_kernel<<<144, 256, 0, stream>>>(w, bp);
    nchw2nhwc<<<4096, 256, 0, stream>>>(x, xt);

    dcn_mfma<<<512, 256, 0, stream>>>(xt, off, bp, out);
}

// Round 10
// 63.001 us; speedup vs baseline: 1.4521x; 1.1208x over previous
//
#include <hip/hip_runtime.h>

#define H_ 128
#define W_ 128
#define HW 16384
#define C_ 64
#define O_ 64
#define N_ 8

typedef __attribute__((ext_vector_type(4))) float f32x4;
typedef __attribute__((ext_vector_type(2))) _Float16 f16x2;
typedef __attribute__((ext_vector_type(8))) _Float16 f16x8;

__device__ __forceinline__ unsigned short f2h(float f) {
    union { _Float16 h; unsigned short u; } c;
    c.h = (_Float16)f;
    return c.u;
}

// ---- prep 1: x NCHW fp32 -> xt NHWC f16, XCD-aligned (n = bid&7) ----
__global__ __launch_bounds__(256) void nchw2nhwc(const float* __restrict__ x,
                                                 unsigned short* __restrict__ xt) {
    const int bid = blockIdx.x;
    const int n = bid & 7;
    const int rest = bid >> 3;
    const int wt = rest & 3, h = rest >> 2;
    const int w0 = wt * 32;
    __shared__ unsigned short tile[32][65];
    const int tid = threadIdx.x;
    const int wl = tid & 31, cg = tid >> 5;
#pragma unroll
    for (int r = 0; r < 8; ++r) {
        const int c = cg * 8 + r;
        const float v = x[(((size_t)(n * 64 + c) * 128 + h) * 128) + w0 + wl];
        tile[wl][c] = f2h(v);
    }
    __syncthreads();
    const int c2 = tid & 63, wg = tid >> 6;
#pragma unroll
    for (int r = 0; r < 8; ++r) {
        const int w = wg * 8 + r;
        xt[(((size_t)(n * 128 + h) * 128 + w0 + w) << 6) + c2] = tile[w][c2];
    }
}

// ---- prep 2: weight [O][C][3][3] fp32 -> B-fragment-packed f16 ----
// ushort idx = q*512 + lane*8 + i ; q = (j*2+h)*4 + ot
// o = ot*16 + (lane&15) ; c = h*32 + (lane>>4)*8 + i
__global__ void bpack_kernel(const float* __restrict__ w, unsigned short* __restrict__ bp) {
    const int idx = blockIdx.x * 256 + threadIdx.x;
    if (idx >= 36864) return;
    const int i = idx & 7;
    const int lane = (idx >> 3) & 63;
    const int ot = (idx >> 9) & 3;
    const int h = (idx >> 11) & 1;
    const int j = idx >> 12;
    const int o = ot * 16 + (lane & 15);
    const int c = h * 32 + (lane >> 4) * 8 + i;
    bp[idx] = f2h(w[(o * 64 + c) * 9 + j]);
}

// ---- main: 16(w)x8(h) output tile per block -> 1024 blocks = 4 blocks/CU ----
// (round 9 lesson: grid of 512 capped residency at 2 blocks/CU no matter what
//  launch_bounds allowed; stalls dominated at 2 waves/SIMD.)
// Halo 20(y)x28(x) positions, 32 ch per h-half: 20*28*64B = 35,840 B LDS.
// 4 blocks x 35.8KB = 143KB <= 160KB; VGPR must stay <=128 for 4 waves/SIMD.
__global__ __launch_bounds__(256, 4) void dcn_mfma(const unsigned short* __restrict__ xt,
                                                   const float* __restrict__ off,
                                                   const unsigned short* __restrict__ bp,
                                                   float* __restrict__ out) {
    __shared__ uint4 lds4[2240];   // 20*28 positions * 4 chunks

    const int tid = threadIdx.x;
    const int lane = tid & 63;
    const int wid = tid >> 6;
    const int lrow = lane & 15;   // pixel within strip (A-row); o in epilogue
    const int lgrp = lane >> 4;   // k-group

    const int bid = blockIdx.x;
    const int n = bid & 7;               // XCD-pinned image
    const int tile = bid >> 3;           // 0..127
    const int t   = (tile >> 3) << 3;    // tile row origin (16 row-tiles of 8)
    const int tx0 = (tile & 7) << 4;     // tile col origin (8 col-tiles of 16)

    const unsigned short* xn = xt + (size_t)n * (HW * 64);
    const unsigned char* xb = (const unsigned char*)xn;
    const f16x8* bg = (const f16x8*)bp;
    const float* offn = off + (size_t)n * 18 * HW;

    f32x4 acc[2][4];
#pragma unroll
    for (int q = 0; q < 2; ++q)
#pragma unroll
        for (int r = 0; r < 4; ++r) acc[q][r] = (f32x4){0.f, 0.f, 0.f, 0.f};

#pragma unroll 1
    for (int h = 0; h < 2; ++h) {
        if (h) __syncthreads();   // all reads of previous half done before overwrite
        // ---- stage halo half (32 channels) : coalesced global -> LDS ----
        for (int c = tid; c < 560; c += 256) {
            const int ry = c / 28, rx = c - ry * 28;
            const int gy = min(max(t - 6 + ry, 0), 127);
            const int gx = min(max(tx0 - 6 + rx, 0), 127);
            const uint4* src = (const uint4*)(xn + ((((gy << 7) + gx) << 6) | (h << 5)));
            const int d = c << 2, sw = rx & 3;
#pragma unroll
            for (int sub = 0; sub < 4; ++sub) lds4[d + (sub ^ sw)] = src[sub];
        }
        __syncthreads();

        // ---- compute: 2 strips per wave (strip = one output row), 9 taps, K-half h ----
#pragma unroll
        for (int q = 0; q < 2; ++q) {
            const int ho = t + (wid << 1) + q;
            const int wo = tx0 + lrow;
            const int pix = (ho << 7) + wo;
            const float fho = (float)(ho - 1);
            const float fwo = (float)(wo - 1);

#pragma unroll 1
            for (int jo = 0; jo < 3; ++jo) {   // kh = jo
                const float* ob = offn + (size_t)(6 * jo) * HW + pix;
                const float o0 = ob[0];
                const float o1 = ob[(size_t)1 * HW];
                const float o2 = ob[(size_t)2 * HW];
                const float o3 = ob[(size_t)3 * HW];
                const float o4 = ob[(size_t)4 * HW];
                const float o5 = ob[(size_t)5 * HW];
#pragma unroll
                for (int ji = 0; ji < 3; ++ji) {   // kw = ji
                    const float oy = (ji == 0) ? o0 : (ji == 1) ? o2 : o4;
                    const float ox = (ji == 0) ? o1 : (ji == 1) ? o3 : o5;
                    const float py = fho + (float)jo + oy;
                    const float px = fwo + (float)ji + ox;
                    const float y0f = floorf(py), x0f = floorf(px);
                    const float wy = py - y0f, wx = px - x0f;
                    const int y0 = (int)y0f, xx0 = (int)x0f;
                    const bool vy0 = (unsigned)y0 < 128u;
                    const bool vy1 = (unsigned)(y0 + 1) < 128u;
                    const bool vx0 = (unsigned)xx0 < 128u;
                    const bool vx1 = (unsigned)(xx0 + 1) < 128u;
                    const int y0c = min(max(y0, 0), 127), y1c = min(max(y0 + 1, 0), 127);
                    const int x0c = min(max(xx0, 0), 127), x1c = min(max(xx0 + 1, 0), 127);
                    const float s00 = (1.f - wy) * (1.f - wx) * ((vy0 & vx0) ? 1.f : 0.f);
                    const float s01 = (1.f - wy) * wx * ((vy0 & vx1) ? 1.f : 0.f);
                    const float s10 = wy * (1.f - wx) * ((vy1 & vx0) ? 1.f : 0.f);
                    const float s11 = wy * wx * ((vy1 & vx1) ? 1.f : 0.f);
                    const _Float16 h00 = (_Float16)s00, h01 = (_Float16)s01;
                    const _Float16 h10 = (_Float16)s10, h11 = (_Float16)s11;
                    const f16x2 W00 = {h00, h00}, W01 = {h01, h01};
                    const f16x2 W10 = {h10, h10}, W11 = {h11, h11};

                    // in-halo slots (y margin 6, rows 0..19; x margin 6, cols 0..27)
                    const int sy0 = y0c - t + 6, sy1 = y1c - t + 6;
                    const int sx0 = x0c - tx0 + 6, sx1 = x1c - tx0 + 6;
                    const bool ok = ((unsigned)sy0 <= 19u) & ((unsigned)sy1 <= 19u) &
                                    ((unsigned)sx0 <= 27u) & ((unsigned)sx1 <= 27u);
                    const int cy0 = min(max(sy0, 0), 19), cy1 = min(max(sy1, 0), 19);
                    const int cx0 = min(max(sx0, 0), 27), cx1 = min(max(sx1, 0), 27);
                    const int r0 = cy0 * 28, r1 = cy1 * 28;
                    const int gx0 = lgrp ^ (cx0 & 3), gx1 = lgrp ^ (cx1 & 3);
                    uint4 T00 = lds4[((r0 + cx0) << 2) + gx0];
                    uint4 T01 = lds4[((r0 + cx1) << 2) + gx1];
                    uint4 T10 = lds4[((r1 + cx0) << 2) + gx0];
                    uint4 T11 = lds4[((r1 + cx1) << 2) + gx1];
                    if (!__all(ok)) {   // rare: offset beyond halo -> exact global path
                        if (!ok) {
                            const unsigned char* p = xb + ((((y0c << 7) + x0c) << 7) | (h << 6)) + (lgrp << 4);
                            const int dxo = (x1c - x0c) << 7;
                            const int dyo = (y1c - y0c) << 14;
                            T00 = *(const uint4*)p;
                            T01 = *(const uint4*)(p + dxo);
                            T10 = *(const uint4*)(p + dyo);
                            T11 = *(const uint4*)(p + dyo + dxo);
                        }
                    }
                    union { uint4 u; f16x2 h2[4]; f16x8 v; } A, U00, U01, U10, U11;
                    U00.u = T00; U01.u = T01; U10.u = T10; U11.u = T11;
#pragma unroll
                    for (int k = 0; k < 4; ++k)
                        A.h2[k] = U00.h2[k] * W00 + U01.h2[k] * W01
                                + U10.h2[k] * W10 + U11.h2[k] * W11;
                    const int j = jo * 3 + ji;
                    const int fb = ((j * 2 + h) << 8) + lane;   // ((j*2+h)*4)*64 + lane
                    acc[q][0] = __builtin_amdgcn_mfma_f32_16x16x32_f16(A.v, bg[fb],       acc[q][0], 0, 0, 0);
                    acc[q][1] = __builtin_amdgcn_mfma_f32_16x16x32_f16(A.v, bg[fb + 64],  acc[q][1], 0, 0, 0);
                    acc[q][2] = __builtin_amdgcn_mfma_f32_16x16x32_f16(A.v, bg[fb + 128], acc[q][2], 0, 0, 0);
                    acc[q][3] = __builtin_amdgcn_mfma_f32_16x16x32_f16(A.v, bg[fb + 192], acc[q][3], 0, 0, 0);
                }
            }
        }
    }

    // epilogue: o = qo*16 + lrow plane, pixel = strip_base + lgrp*4 + r (validated r2-r9)
#pragma unroll
    for (int q = 0; q < 2; ++q) {
        float* opb = out + (size_t)n * (O_ * HW) + ((t + (wid << 1) + q) << 7) + tx0 + lgrp * 4;
        *(f32x4*)(opb + (size_t)(0 * 16 + lrow) * HW) = acc[q][0];
        *(f32x4*)(opb + (size_t)(1 * 16 + lrow) * HW) = acc[q][1];
        *(f32x4*)(opb + (size_t)(2 * 16 + lrow) * HW) = acc[q][2];
        *(f32x4*)(opb + (size_t)(3 * 16 + lrow) * HW) = acc[q][3];
    }
}

extern "C" void kernel_launch(void* const* d_in, const int* in_sizes, int n_in,
                              void* d_out, int out_size, void* d_ws, size_t ws_size,
                              hipStream_t stream) {
    const float* x = (const float*)d_in[0];
    const float* off = (const float*)d_in[1];
    const float* w = (const float*)d_in[2];
    float* out = (float*)d_out;

    unsigned short* bp = (unsigned short*)d_ws;                  // 73728 B
    unsigned short* xt = (unsigned short*)((char*)d_ws + 73728); // 16.8 MB

    bpack_kernel<<<144, 256, 0, stream>>>(w, bp);
    nchw2nhwc<<<4096, 256, 0, stream>>>(x, xt);

    dcn_mfma<<<1024, 256, 0, stream>>>(xt, off, bp, out);
}